// Round 1
// baseline (6061.097 us; speedup 1.0000x reference)
//
#include <hip/hip_runtime.h>

#define B_N 16384
#define G_N 8192
#define D_N 1024

// ---------------- group inverse norms: invn[j] = 1/max(||g_j||, eps) ----------------
__global__ __launch_bounds__(256) void k_norms(const float* __restrict__ g,
                                               float* __restrict__ invn) {
    const int j = blockIdx.x;
    const int t = threadIdx.x;
    const float4 v = *reinterpret_cast<const float4*>(&g[(size_t)j * D_N + t * 4]);
    float s = v.x * v.x + v.y * v.y + v.z * v.z + v.w * v.w;
#pragma unroll
    for (int off = 32; off >= 1; off >>= 1) s += __shfl_down(s, off, 64);
    __shared__ float wsum[4];
    if ((t & 63) == 0) wsum[t >> 6] = s;
    __syncthreads();
    if (t == 0) {
        const float tot = wsum[0] + wsum[1] + wsum[2] + wsum[3];
        invn[j] = 1.0f / fmaxf(sqrtf(tot), 1e-12f);
    }
}

// ---------------- fused GEMM + argmax: assign[i] = argmax_j (x_i . g_j) * invn[j] ----------------
// M=16384, N=8192, K=1024. Tile: TM=64 x TN=64, BK=32, 256 threads, 4x4 microtile.
constexpr int TM = 64, TN = 64, BK = 32;

__global__ __launch_bounds__(256) void k_argmax(const float* __restrict__ x,
                                                const float* __restrict__ g,
                                                const float* __restrict__ invn,
                                                int* __restrict__ assign) {
    __shared__ __align__(16) float As[BK][TM + 4];  // +4 pad: 2-way (free) LDS conflicts, keeps 16B align
    __shared__ __align__(16) float Bs[BK][TN + 4];

    const int t = threadIdx.x;
    const int tx = t & 15;   // owns cols tx*4 .. tx*4+3
    const int ty = t >> 4;   // owns rows ty*4 .. ty*4+3
    const int row0 = blockIdx.x * TM;

    const int r_a = t >> 3;  // staging: row within tile (0..31), p adds 32
    const int c4  = t & 7;   // staging: float4 column (0..7) within BK=32

    float bestv[4];
    int   besti[4];
#pragma unroll
    for (int i = 0; i < 4; ++i) { bestv[i] = -3.0e38f; besti[i] = 0; }

    for (int jt = 0; jt < G_N / TN; ++jt) {
        float acc[4][4] = {};
        for (int kt = 0; kt < D_N / BK; ++kt) {
#pragma unroll
            for (int p = 0; p < 2; ++p) {
                const int r = r_a + p * 32;
                const float4 va = *reinterpret_cast<const float4*>(
                    &x[(size_t)(row0 + r) * D_N + kt * BK + c4 * 4]);
                As[c4 * 4 + 0][r] = va.x;
                As[c4 * 4 + 1][r] = va.y;
                As[c4 * 4 + 2][r] = va.z;
                As[c4 * 4 + 3][r] = va.w;
                const float4 vb = *reinterpret_cast<const float4*>(
                    &g[(size_t)(jt * TN + r) * D_N + kt * BK + c4 * 4]);
                Bs[c4 * 4 + 0][r] = vb.x;
                Bs[c4 * 4 + 1][r] = vb.y;
                Bs[c4 * 4 + 2][r] = vb.z;
                Bs[c4 * 4 + 3][r] = vb.w;
            }
            __syncthreads();
#pragma unroll
            for (int k = 0; k < BK; ++k) {
                const float4 a = *reinterpret_cast<const float4*>(&As[k][ty * 4]);
                const float4 b = *reinterpret_cast<const float4*>(&Bs[k][tx * 4]);
                const float av[4] = {a.x, a.y, a.z, a.w};
                const float bv[4] = {b.x, b.y, b.z, b.w};
#pragma unroll
                for (int i = 0; i < 4; ++i)
#pragma unroll
                    for (int jj = 0; jj < 4; ++jj) acc[i][jj] += av[i] * bv[jj];
            }
            __syncthreads();
        }
        // epilogue for this N-tile: scale by 1/||g_j||, update running argmax
#pragma unroll
        for (int jj = 0; jj < 4; ++jj) {
            const int col = jt * TN + tx * 4 + jj;
            const float s = invn[col];
#pragma unroll
            for (int i = 0; i < 4; ++i) {
                const float v = acc[i][jj] * s;
                if (v > bestv[i]) { bestv[i] = v; besti[i] = col; }  // ascending col scan -> first-max
            }
        }
    }
    // reduce across the 16 tx-lanes sharing each row (xor over lane bits 0..3)
#pragma unroll
    for (int m = 1; m < 16; m <<= 1) {
#pragma unroll
        for (int i = 0; i < 4; ++i) {
            const float ov = __shfl_xor(bestv[i], m, 64);
            const int   oi = __shfl_xor(besti[i], m, 64);
            if (ov > bestv[i] || (ov == bestv[i] && oi < besti[i])) { bestv[i] = ov; besti[i] = oi; }
        }
    }
    if (tx == 0) {
#pragma unroll
        for (int i = 0; i < 4; ++i) assign[row0 + ty * 4 + i] = besti[i];
    }
}

// ---------------- counts[j] = #samples assigned to j ----------------
__global__ void k_counts(const int* __restrict__ assign, int* __restrict__ counts) {
    const int i = blockIdx.x * blockDim.x + threadIdx.x;
    if (i < B_N) atomicAdd(&counts[assign[i]], 1);
}

// ---------------- contrib[a] += x_i / counts[a] (atomic scatter) ----------------
__global__ __launch_bounds__(256) void k_scatter(const float* __restrict__ x,
                                                 const int* __restrict__ assign,
                                                 const int* __restrict__ counts,
                                                 float* __restrict__ contrib) {
    const int i = blockIdx.x;
    const int a = assign[i];
    const float scale = 1.0f / (float)counts[a];
    const int t = threadIdx.x;
    const float4 v = *reinterpret_cast<const float4*>(&x[(size_t)i * D_N + t * 4]);
    float* dst = &contrib[(size_t)a * D_N + t * 4];
    atomicAdd(dst + 0, v.x * scale);
    atomicAdd(dst + 1, v.y * scale);
    atomicAdd(dst + 2, v.z * scale);
    atomicAdd(dst + 3, v.w * scale);
}

// ---------------- out[j] = normalize( (counts[j]>0 ? 0.99 : 1)*g_j + 0.01*contrib_j ) ----------------
__global__ __launch_bounds__(256) void k_finalize(const float* __restrict__ g,
                                                  const int* __restrict__ counts,
                                                  float* __restrict__ out) {
    const int j = blockIdx.x;
    const int t = threadIdx.x;
    const float sc = (counts[j] > 0) ? 0.99f : 1.0f;
    const float4 gv = *reinterpret_cast<const float4*>(&g[(size_t)j * D_N + t * 4]);
    const float4 cv = *reinterpret_cast<const float4*>(&out[(size_t)j * D_N + t * 4]);
    float4 gf;
    gf.x = sc * gv.x + 0.01f * cv.x;
    gf.y = sc * gv.y + 0.01f * cv.y;
    gf.z = sc * gv.z + 0.01f * cv.z;
    gf.w = sc * gv.w + 0.01f * cv.w;
    float s = gf.x * gf.x + gf.y * gf.y + gf.z * gf.z + gf.w * gf.w;
#pragma unroll
    for (int off = 32; off >= 1; off >>= 1) s += __shfl_down(s, off, 64);
    __shared__ float wsum[4];
    __shared__ float s_inv;
    if ((t & 63) == 0) wsum[t >> 6] = s;
    __syncthreads();
    if (t == 0) s_inv = 1.0f / fmaxf(sqrtf(wsum[0] + wsum[1] + wsum[2] + wsum[3]), 1e-12f);
    __syncthreads();
    gf.x *= s_inv; gf.y *= s_inv; gf.z *= s_inv; gf.w *= s_inv;
    *reinterpret_cast<float4*>(&out[(size_t)j * D_N + t * 4]) = gf;
}

extern "C" void kernel_launch(void* const* d_in, const int* in_sizes, int n_in,
                              void* d_out, int out_size, void* d_ws, size_t ws_size,
                              hipStream_t stream) {
    const float* x = (const float*)d_in[0];          // [16384, 1024]
    const float* g = (const float*)d_in[1];          // [8192, 1024]
    float* out = (float*)d_out;                      // [8192, 1024], doubles as contrib accumulator

    char* ws = (char*)d_ws;
    float* invn   = (float*)ws;                        // 8192 f32
    int*   assign = (int*)(ws + (size_t)G_N * 4);      // 16384 i32
    int*   counts = (int*)(ws + (size_t)(G_N + B_N) * 4);  // 8192 i32

    hipMemsetAsync(out, 0, (size_t)G_N * D_N * sizeof(float), stream);
    hipMemsetAsync(counts, 0, (size_t)G_N * sizeof(int), stream);

    k_norms<<<G_N, 256, 0, stream>>>(g, invn);
    k_argmax<<<B_N / TM, 256, 0, stream>>>(x, g, invn, assign);
    k_counts<<<B_N / 256, 256, 0, stream>>>(assign, counts);
    k_scatter<<<B_N, 256, 0, stream>>>(x, assign, counts, out);
    k_finalize<<<G_N, 256, 0, stream>>>(g, counts, out);
}

// Round 2
// 1242.201 us; speedup vs baseline: 4.8793x; 4.8793x over previous
//
#include <hip/hip_runtime.h>
#include <float.h>

#define B_N 16384
#define G_N 8192
#define D_N 1024

typedef unsigned short u16;
typedef __attribute__((ext_vector_type(8))) short short8;
typedef __attribute__((ext_vector_type(4))) float f32x4;

#define AS1 __attribute__((address_space(1)))
#define AS3 __attribute__((address_space(3)))

// ======================= common small kernels =======================

// invn[j] = 1/max(||g_j||, eps)
__global__ __launch_bounds__(256) void k_norms(const float* __restrict__ g,
                                               float* __restrict__ invn) {
    const int j = blockIdx.x;
    const int t = threadIdx.x;
    const float4 v = *reinterpret_cast<const float4*>(&g[(size_t)j * D_N + t * 4]);
    float s = v.x * v.x + v.y * v.y + v.z * v.z + v.w * v.w;
#pragma unroll
    for (int off = 32; off >= 1; off >>= 1) s += __shfl_down(s, off, 64);
    __shared__ float wsum[4];
    if ((t & 63) == 0) wsum[t >> 6] = s;
    __syncthreads();
    if (t == 0) {
        const float tot = wsum[0] + wsum[1] + wsum[2] + wsum[3];
        invn[j] = 1.0f / fmaxf(sqrtf(tot), 1e-12f);
    }
}

__global__ void k_counts(const int* __restrict__ assign, int* __restrict__ counts) {
    const int i = blockIdx.x * blockDim.x + threadIdx.x;
    if (i < B_N) atomicAdd(&counts[assign[i]], 1);
}

__global__ __launch_bounds__(256) void k_scatter(const float* __restrict__ x,
                                                 const int* __restrict__ assign,
                                                 const int* __restrict__ counts,
                                                 float* __restrict__ contrib) {
    const int i = blockIdx.x;
    const int a = assign[i];
    const float scale = 1.0f / (float)counts[a];
    const int t = threadIdx.x;
    const float4 v = *reinterpret_cast<const float4*>(&x[(size_t)i * D_N + t * 4]);
    float* dst = &contrib[(size_t)a * D_N + t * 4];
    atomicAdd(dst + 0, v.x * scale);
    atomicAdd(dst + 1, v.y * scale);
    atomicAdd(dst + 2, v.z * scale);
    atomicAdd(dst + 3, v.w * scale);
}

__global__ __launch_bounds__(256) void k_finalize(const float* __restrict__ g,
                                                  const int* __restrict__ counts,
                                                  float* __restrict__ out) {
    const int j = blockIdx.x;
    const int t = threadIdx.x;
    const float sc = (counts[j] > 0) ? 0.99f : 1.0f;
    const float4 gv = *reinterpret_cast<const float4*>(&g[(size_t)j * D_N + t * 4]);
    const float4 cv = *reinterpret_cast<const float4*>(&out[(size_t)j * D_N + t * 4]);
    float4 gf;
    gf.x = sc * gv.x + 0.01f * cv.x;
    gf.y = sc * gv.y + 0.01f * cv.y;
    gf.z = sc * gv.z + 0.01f * cv.z;
    gf.w = sc * gv.w + 0.01f * cv.w;
    float s = gf.x * gf.x + gf.y * gf.y + gf.z * gf.z + gf.w * gf.w;
#pragma unroll
    for (int off = 32; off >= 1; off >>= 1) s += __shfl_down(s, off, 64);
    __shared__ float wsum[4];
    __shared__ float s_inv;
    if ((t & 63) == 0) wsum[t >> 6] = s;
    __syncthreads();
    if (t == 0) s_inv = 1.0f / fmaxf(sqrtf(wsum[0] + wsum[1] + wsum[2] + wsum[3]), 1e-12f);
    __syncthreads();
    gf.x *= s_inv; gf.y *= s_inv; gf.z *= s_inv; gf.w *= s_inv;
    *reinterpret_cast<float4*>(&out[(size_t)j * D_N + t * 4]) = gf;
}

// ======================= bf16 split prep =======================

__device__ inline u16 f2bf_rtn(float f) {
    unsigned u = __float_as_uint(f);
    unsigned r = u + 0x7fffu + ((u >> 16) & 1u);
    return (u16)(r >> 16);
}
__device__ inline float bf2f(u16 h) { return __uint_as_float(((unsigned)h) << 16); }

// split fp32 -> (hi, lo) bf16; one float4 per thread
__global__ __launch_bounds__(256) void k_split(const float* __restrict__ src,
                                               u16* __restrict__ hi,
                                               u16* __restrict__ lo) {
    const size_t i4 = (size_t)blockIdx.x * 256 + threadIdx.x;
    const float4 v = *reinterpret_cast<const float4*>(&src[i4 * 4]);
    u16 h[4], l[4];
    const float f[4] = {v.x, v.y, v.z, v.w};
#pragma unroll
    for (int j = 0; j < 4; ++j) {
        h[j] = f2bf_rtn(f[j]);
        l[j] = f2bf_rtn(f[j] - bf2f(h[j]));
    }
    ushort4 hv = make_ushort4(h[0], h[1], h[2], h[3]);
    ushort4 lv = make_ushort4(l[0], l[1], l[2], l[3]);
    *reinterpret_cast<ushort4*>(&hi[i4 * 4]) = hv;
    *reinterpret_cast<ushort4*>(&lo[i4 * 4]) = lv;
}

// ======================= MFMA GEMM + fused argmax =======================
// C = x . g^T via bf16x3 split: x_hi*g_hi + x_hi*g_lo + x_lo*g_hi.
// 128x128 tile, BK=32, 4 waves (2x2 of 64x64), mfma_f32_16x16x32_bf16.
// Grid: 128 M-blocks x NSPLIT N-splits; split s pinned to XCD s via swizzle
// so each XCD's 4MiB L2 holds exactly its 4MiB g-panel (hi+lo).

constexpr int NSPLIT = 8;           // 8192/8 = 1024 cols per block = 8 jt tiles
constexpr int JT_PER = G_N / NSPLIT / 128;  // 8

__global__ __launch_bounds__(256, 2) void k_mfma_argmax(
    const u16* __restrict__ x_hi, const u16* __restrict__ x_lo,
    const u16* __restrict__ g_hi, const u16* __restrict__ g_lo,
    const float* __restrict__ invn,
    float* __restrict__ pbv, int* __restrict__ pbi) {

    // 4 arrays (A_hi, A_lo, B_hi, B_lo), each 128 rows x 32 k, fragment-major:
    // 16B chunk c = (rowgrp*4 + kslot)*16 + rowin; frag read for rowgrp rg is
    // chunks [rg*64 + lane] -> contiguous 1KiB per wave, conflict-free.
    __shared__ __align__(16) u16 lds[4][4096];

    const int bid = blockIdx.x;                 // 0..1023
    const int swz = (bid & 7) * (128 * NSPLIT / 8) + (bid >> 3);
    const int split = swz >> 7;                 // 0..7: one split per XCD
    const int mblk = swz & 127;                 // 0..127

    const int t = threadIdx.x;
    const int lane = t & 63;
    const int w = t >> 6;                       // wave 0..3
    const int wr = w >> 1, wc = w & 1;          // 2x2 wave grid over 128x128
    const int rl = lane & 15;                   // row-in-group / col-in-frag
    const int kg = lane >> 4;                   // k-slot 0..3

    const u16* stage_src = (w == 0) ? x_hi : (w == 1) ? x_lo : (w == 2) ? g_hi : g_lo;
    const int a_row0 = mblk * 128;

    float bestv[4][4];
    int   besti[4][4];
#pragma unroll
    for (int m = 0; m < 4; ++m)
#pragma unroll
        for (int j = 0; j < 4; ++j) { bestv[m][j] = -FLT_MAX; besti[m][j] = 0; }

    for (int jt = 0; jt < JT_PER; ++jt) {
        const int col0 = split * 1024 + jt * 128;
        const int stage_row0 = (w < 2) ? a_row0 : col0;  // A waves stage x rows, B waves stage g rows

        f32x4 acc[4][4];
#pragma unroll
        for (int m = 0; m < 4; ++m)
#pragma unroll
            for (int n = 0; n < 4; ++n) acc[m][n] = (f32x4){0.f, 0.f, 0.f, 0.f};

        for (int kt = 0; kt < D_N / 32; ++kt) {
            const int k0 = kt * 32 + kg * 8;
            // stage: wave w fills array w (8 x 1KiB wave-chunks)
#pragma unroll
            for (int i = 0; i < 8; ++i) {
                const int row = stage_row0 + i * 16 + rl;
                const u16* src = stage_src + (size_t)row * D_N + k0;
                __builtin_amdgcn_global_load_lds(
                    (const AS1 void*)src,
                    (AS3 void*)&lds[w][i * 512],
                    16, 0, 0);
            }
            __syncthreads();

            short8 a_hi[4], a_lo[4], b_hi[4], b_lo[4];
#pragma unroll
            for (int m = 0; m < 4; ++m) {
                const int ao = ((wr * 4 + m) * 64 + lane) * 8;
                const int bo = ((wc * 4 + m) * 64 + lane) * 8;
                a_hi[m] = *reinterpret_cast<const short8*>(&lds[0][ao]);
                a_lo[m] = *reinterpret_cast<const short8*>(&lds[1][ao]);
                b_hi[m] = *reinterpret_cast<const short8*>(&lds[2][bo]);
                b_lo[m] = *reinterpret_cast<const short8*>(&lds[3][bo]);
            }
#pragma unroll
            for (int m = 0; m < 4; ++m)
#pragma unroll
                for (int n = 0; n < 4; ++n)
                    acc[m][n] = __builtin_amdgcn_mfma_f32_16x16x32_bf16(a_hi[m], b_hi[n], acc[m][n], 0, 0, 0);
#pragma unroll
            for (int m = 0; m < 4; ++m)
#pragma unroll
                for (int n = 0; n < 4; ++n)
                    acc[m][n] = __builtin_amdgcn_mfma_f32_16x16x32_bf16(a_hi[m], b_lo[n], acc[m][n], 0, 0, 0);
#pragma unroll
            for (int m = 0; m < 4; ++m)
#pragma unroll
                for (int n = 0; n < 4; ++n)
                    acc[m][n] = __builtin_amdgcn_mfma_f32_16x16x32_bf16(a_lo[m], b_hi[n], acc[m][n], 0, 0, 0);
            __syncthreads();
        }

        // epilogue: scale by invn, running argmax (ascending col -> first-max ties)
#pragma unroll
        for (int n = 0; n < 4; ++n) {
            const int col = col0 + wc * 64 + n * 16 + rl;
            const float s = invn[col];
#pragma unroll
            for (int m = 0; m < 4; ++m)
#pragma unroll
                for (int j = 0; j < 4; ++j) {
                    const float v = acc[m][n][j] * s;
                    if (v > bestv[m][j]) { bestv[m][j] = v; besti[m][j] = col; }
                }
        }
    }

    // reduce across the 16 lanes (lane&15) sharing each output row
#pragma unroll
    for (int msk = 1; msk < 16; msk <<= 1) {
#pragma unroll
        for (int m = 0; m < 4; ++m)
#pragma unroll
            for (int j = 0; j < 4; ++j) {
                const float ov = __shfl_xor(bestv[m][j], msk, 64);
                const int   oi = __shfl_xor(besti[m][j], msk, 64);
                if (ov > bestv[m][j] || (ov == bestv[m][j] && oi < besti[m][j])) {
                    bestv[m][j] = ov; besti[m][j] = oi;
                }
            }
    }
    if (rl == 0) {
        const int e = split * 2 + wc;   // 16 partial entries per row
#pragma unroll
        for (int m = 0; m < 4; ++m)
#pragma unroll
            for (int j = 0; j < 4; ++j) {
                const int row = a_row0 + wr * 64 + m * 16 + kg * 4 + j;
                pbv[(size_t)row * 16 + e] = bestv[m][j];
                pbi[(size_t)row * 16 + e] = besti[m][j];
            }
    }
}

__global__ void k_reduce_best(const float* __restrict__ pbv, const int* __restrict__ pbi,
                              int* __restrict__ assign) {
    const int r = blockIdx.x * blockDim.x + threadIdx.x;
    if (r >= B_N) return;
    float bv = -FLT_MAX; int bi = 0x7fffffff;
#pragma unroll
    for (int e = 0; e < 16; ++e) {
        const float v = pbv[(size_t)r * 16 + e];
        const int   i = pbi[(size_t)r * 16 + e];
        if (v > bv || (v == bv && i < bi)) { bv = v; bi = i; }
    }
    assign[r] = bi;
}

// ======================= fallback fp32 argmax (round-1 path) =======================

__global__ __launch_bounds__(256) void k_argmax_fp32(const float* __restrict__ x,
                                                     const float* __restrict__ g,
                                                     const float* __restrict__ invn,
                                                     int* __restrict__ assign) {
    __shared__ __align__(16) float As[32][68];
    __shared__ __align__(16) float Bs[32][68];
    const int t = threadIdx.x;
    const int tx = t & 15;
    const int ty = t >> 4;
    const int row0 = blockIdx.x * 64;
    const int r_a = t >> 3;
    const int c4 = t & 7;
    float bestv[4]; int besti[4];
#pragma unroll
    for (int i = 0; i < 4; ++i) { bestv[i] = -3.0e38f; besti[i] = 0; }
    for (int jt = 0; jt < G_N / 64; ++jt) {
        float acc[4][4] = {};
        for (int kt = 0; kt < D_N / 32; ++kt) {
#pragma unroll
            for (int p = 0; p < 2; ++p) {
                const int r = r_a + p * 32;
                const float4 va = *reinterpret_cast<const float4*>(&x[(size_t)(row0 + r) * D_N + kt * 32 + c4 * 4]);
                As[c4 * 4 + 0][r] = va.x; As[c4 * 4 + 1][r] = va.y; As[c4 * 4 + 2][r] = va.z; As[c4 * 4 + 3][r] = va.w;
                const float4 vb = *reinterpret_cast<const float4*>(&g[(size_t)(jt * 64 + r) * D_N + kt * 32 + c4 * 4]);
                Bs[c4 * 4 + 0][r] = vb.x; Bs[c4 * 4 + 1][r] = vb.y; Bs[c4 * 4 + 2][r] = vb.z; Bs[c4 * 4 + 3][r] = vb.w;
            }
            __syncthreads();
#pragma unroll
            for (int k = 0; k < 32; ++k) {
                const float4 a = *reinterpret_cast<const float4*>(&As[k][ty * 4]);
                const float4 b = *reinterpret_cast<const float4*>(&Bs[k][tx * 4]);
                const float av[4] = {a.x, a.y, a.z, a.w};
                const float bv[4] = {b.x, b.y, b.z, b.w};
#pragma unroll
                for (int i = 0; i < 4; ++i)
#pragma unroll
                    for (int jj = 0; jj < 4; ++jj) acc[i][jj] += av[i] * bv[jj];
            }
            __syncthreads();
        }
#pragma unroll
        for (int jj = 0; jj < 4; ++jj) {
            const int col = jt * 64 + tx * 4 + jj;
            const float s = invn[col];
#pragma unroll
            for (int i = 0; i < 4; ++i) {
                const float v = acc[i][jj] * s;
                if (v > bestv[i]) { bestv[i] = v; besti[i] = col; }
            }
        }
    }
#pragma unroll
    for (int m = 1; m < 16; m <<= 1) {
#pragma unroll
        for (int i = 0; i < 4; ++i) {
            const float ov = __shfl_xor(bestv[i], m, 64);
            const int oi = __shfl_xor(besti[i], m, 64);
            if (ov > bestv[i] || (ov == bestv[i] && oi < besti[i])) { bestv[i] = ov; besti[i] = oi; }
        }
    }
    if (tx == 0) {
#pragma unroll
        for (int i = 0; i < 4; ++i) assign[row0 + ty * 4 + i] = besti[i];
    }
}

// ======================= launch =======================

extern "C" void kernel_launch(void* const* d_in, const int* in_sizes, int n_in,
                              void* d_out, int out_size, void* d_ws, size_t ws_size,
                              hipStream_t stream) {
    const float* x = (const float*)d_in[0];   // [16384, 1024]
    const float* g = (const float*)d_in[1];   // [8192, 1024]
    float* out = (float*)d_out;               // [8192, 1024]; doubles as contrib accumulator

    char* ws = (char*)d_ws;
    // MFMA-path workspace layout (bytes)
    u16*  x_hi  = (u16*)(ws);                       // 32 MiB
    u16*  x_lo  = (u16*)(ws + 33554432);            // 32 MiB
    u16*  g_hi  = (u16*)(ws + 67108864);            // 16 MiB
    u16*  g_lo  = (u16*)(ws + 83886080);            // 16 MiB
    float* invn = (float*)(ws + 100663296);         // 32 KiB
    int* assign = (int*)(ws + 100696064);           // 64 KiB
    int* counts = (int*)(ws + 100761600);           // 32 KiB
    float* pbv  = (float*)(ws + 100794368);         // 1 MiB
    int*   pbi  = (int*)(ws + 101842944);           // 1 MiB
    const size_t need = 102891520;

    hipMemsetAsync(out, 0, (size_t)G_N * D_N * sizeof(float), stream);
    hipMemsetAsync(counts, 0, (size_t)G_N * sizeof(int), stream);

    k_norms<<<G_N, 256, 0, stream>>>(g, invn);

    if (ws_size >= need) {
        k_split<<<B_N * D_N / 4 / 256, 256, 0, stream>>>(x, x_hi, x_lo);
        k_split<<<G_N * D_N / 4 / 256, 256, 0, stream>>>(g, g_hi, g_lo);
        k_mfma_argmax<<<128 * NSPLIT, 256, 0, stream>>>(x_hi, x_lo, g_hi, g_lo, invn, pbv, pbi);
        k_reduce_best<<<B_N / 256, 256, 0, stream>>>(pbv, pbi, assign);
    } else {
        // fallback: fp32 vector path (needs only the small scratch region)
        float* invn_f = (float*)ws;
        int* assign_f = (int*)(ws + (size_t)G_N * 4);
        int* counts_f = (int*)(ws + (size_t)(G_N + B_N) * 4);
        hipMemsetAsync(counts_f, 0, (size_t)G_N * sizeof(int), stream);
        k_norms<<<G_N, 256, 0, stream>>>(g, invn_f);
        k_argmax_fp32<<<B_N / 64, 256, 0, stream>>>(x, g, invn_f, assign_f);
        k_counts<<<B_N / 256, 256, 0, stream>>>(assign_f, counts_f);
        k_scatter<<<B_N, 256, 0, stream>>>(x, assign_f, counts_f, out);
        k_finalize<<<G_N, 256, 0, stream>>>(g, counts_f, out);
        return;
    }

    k_counts<<<B_N / 256, 256, 0, stream>>>(assign, counts);
    k_scatter<<<B_N, 256, 0, stream>>>(x, assign, counts, out);
    k_finalize<<<G_N, 256, 0, stream>>>(g, counts, out);
}